// Round 15
// baseline (117.273 us; speedup 1.0000x reference)
//
#include <hip/hip_runtime.h>

typedef _Float16 f16;
typedef _Float16 f16x4 __attribute__((ext_vector_type(4)));
typedef _Float16 f16x8 __attribute__((ext_vector_type(8)));
typedef float    f32x16 __attribute__((ext_vector_type(16)));

#define MFMA(a, b, c) __builtin_amdgcn_mfma_f32_32x32x16_f16((a), (b), (c), 0, 0, 0)

static constexpr int Mg   = 16384;
static constexpr int Bg   = 2;
static constexpr int Dg   = 256;
static constexpr int Hg   = 8;
static constexpr int Cg   = 512;
static constexpr int Ntok = 2048;
// 1/sqrt(32) * log2(e): k_attn softmax uses exp2f directly
static constexpr float QSCALE = 0.25503487f;

typedef __attribute__((address_space(1))) const void gbl_cv;
typedef __attribute__((address_space(3))) void lds_v;

static __device__ __forceinline__ void gll16(const f16* g, f16* l) {
    __builtin_amdgcn_global_load_lds((gbl_cv*)g, (lds_v*)l, 16, 0, 0);
}
static __device__ __forceinline__ f16x8 mk8(f16x4 a, f16x4 b) {
    f16x8 r;
    r[0] = a[0]; r[1] = a[1]; r[2] = a[2]; r[3] = a[3];
    r[4] = b[0]; r[5] = b[1]; r[6] = b[2]; r[7] = b[3];
    return r;
}

// ---------------------------------------------------------------------------
// k_wt: W[k][n] fp32 -> fp16 slabs (validated layouts). First 4096 threads
// also compute per-token inverse mask-count inv[b][t] = 1/(sum mask + 1e-8)
// for the fused segment-mean in k_attn.
// ---------------------------------------------------------------------------
__global__ __launch_bounds__(256) void k_wt(const float* __restrict__ Wq,
                                            const float* __restrict__ Wk,
                                            const float* __restrict__ Wv,
                                            const float* __restrict__ Wo,
                                            const int* __restrict__ uid,
                                            const float* __restrict__ mask,
                                            f16* __restrict__ Wsw,
                                            float* __restrict__ inv) {
    int idx = blockIdx.x * 256 + threadIdx.x;
    int w   = idx >> 16;
    int rem = idx & 65535;
    int k   = rem >> 8;
    int n   = rem & 255;
    if (w < 3) {
        const float* W = (w == 0) ? Wq : (w == 1) ? Wk : Wv;
        int G = (k >> 3) ^ (n & 7);
        Wsw[w * 65536 + n * 256 + (G << 3) + (k & 7)] = (f16)W[k * 256 + n];
    } else {
        Wsw[3 * 65536 + ((k >> 3) * 256 + n) * 8 + (k & 7)] = (f16)Wo[k * 256 + n];
    }
    if (idx < 2 * 2048) {
        int b = idx >> 11, t = idx & 2047;
        const int* u = uid + b * Mg;
        int lo = 0, hi = Mg;
        while (lo < hi) { int mid = (lo + hi) >> 1; if (u[mid] < t) lo = mid + 1; else hi = mid; }
        int lo2 = lo, hi2 = Mg;
        while (lo2 < hi2) { int mid = (lo2 + hi2) >> 1; if (u[mid] < t + 1) lo2 = mid + 1; else hi2 = mid; }
        float cnt = 0.f;
        for (int m = lo; m < lo2; ++m) cnt += mask[b * Mg + m];
        inv[idx] = 1.f / (cnt + 1e-8f);
    }
}

// ---------------------------------------------------------------------------
// k_qkv: A-in-registers GEMM (validated R9/R12 — best measured). 512 blocks,
// 4 waves, 12 steps. First W-tile stage issued BEFORE the A-register loads.
// V written granule-major VW[b][m>>3][d][m&7].
// R13 lesson: 512-thr/(,4) variant spills a[16] — keep 256 thr / (,2).
// ---------------------------------------------------------------------------
__global__ __launch_bounds__(256, 2) void k_qkv(const float* __restrict__ A,
                                                const f16* __restrict__ Wsw,
                                                f16* __restrict__ Qo,
                                                f16* __restrict__ Ko,
                                                f16* __restrict__ VW) {
    __shared__ f16 Ls[2][32 * 256];   // 2 x 16 KB

    const int tid  = threadIdx.x;
    const int d    = blockIdx.x;
    const int lin  = (d & 7) * 64 + (d >> 3);
    const int yt   = lin >> 1;
    const int half = lin & 1;
    const int m0   = yt * 128;
    const int lane = tid & 63, w = tid >> 6;
    const int l31  = lane & 31, hi = lane >> 5;
    const int mrow = m0 + 32 * w + l31;
    const int xr   = l31 & 7;

#define STW(S, BB)                                                             \
    {                                                                          \
        const f16* src = Wsw + ((S) >> 3) * 65536 + (((S) & 7) * 32) * 256;    \
        _Pragma("unroll")                                                      \
        for (int i = 0; i < 4; ++i) {                                          \
            int g2 = i * 256 + tid;                                            \
            gll16(src + g2 * 8, &Ls[BB][g2 * 8]);                              \
        }                                                                      \
    }

    // ---- issue first W stage, then A loads (stage latency hides under A)
    if (half == 0) { STW(0, 0); } else { STW(12, 0); }

    f16x8 a[16];
    const float* ap = A + (size_t)mrow * 256 + 8 * hi;
#pragma unroll
    for (int g = 0; g < 16; ++g) {
        float4 v0 = *reinterpret_cast<const float4*>(ap + 16 * g);
        float4 v1 = *reinterpret_cast<const float4*>(ap + 16 * g + 4);
        f16x8 t;
        t[0] = (f16)v0.x; t[1] = (f16)v0.y; t[2] = (f16)v0.z; t[3] = (f16)v0.w;
        t[4] = (f16)v1.x; t[5] = (f16)v1.y; t[6] = (f16)v1.z; t[7] = (f16)v1.w;
        a[g] = t;
    }

#define QKV_STEP(S, BB)                                                        \
    {                                                                          \
        if ((S) + 1 < s_end) { STW((S) + 1, (BB) ^ 1); }                       \
        f32x16 acc;                                                            \
        _Pragma("unroll")                                                      \
        for (int e = 0; e < 16; ++e) acc[e] = 0.f;                             \
        _Pragma("unroll")                                                      \
        for (int g = 0; g < 16; ++g) {                                         \
            f16x8 bf = *(const f16x8*)&Ls[BB][l31 * 256 +                      \
                                             (((2 * g + hi) ^ xr) << 3)];      \
            acc = MFMA(a[g], bf, acc);                                         \
        }                                                                      \
        const int wix  = (S) >> 3;                                             \
        const int gcol = ((S) & 7) * 32 + l31;                                 \
        const int mb   = m0 + 32 * w + 4 * hi;                                 \
        if (wix == 0) {                                                        \
            _Pragma("unroll")                                                  \
            for (int r = 0; r < 16; ++r)                                       \
                Qo[(size_t)(mb + (r & 3) + 8 * (r >> 2)) * 256 + gcol] =       \
                    (f16)(acc[r] * QSCALE);                                    \
        } else if (wix == 1) {                                                 \
            _Pragma("unroll")                                                  \
            for (int r = 0; r < 16; ++r)                                       \
                Ko[(size_t)(mb + (r & 3) + 8 * (r >> 2)) * 256 + gcol] =       \
                    (f16)acc[r];                                               \
        } else {                                                               \
            _Pragma("unroll")                                                  \
            for (int rq = 0; rq < 4; ++rq) {                                   \
                f16x4 pv = { (f16)acc[rq * 4 + 0], (f16)acc[rq * 4 + 1],       \
                             (f16)acc[rq * 4 + 2], (f16)acc[rq * 4 + 3] };     \
                int mr  = mb + 8 * rq;                                         \
                int bb2 = mr >> 14;                                            \
                int msg = (mr & 16383) >> 3;                                   \
                *reinterpret_cast<f16x4*>(VW + ((size_t)(bb2 * 2048 + msg) *   \
                                          256 + gcol) * 8 + 4 * hi) = pv;      \
            }                                                                  \
        }                                                                      \
        if ((S) + 1 < s_end) {                                                 \
            if (((S) >> 3) == 2) {                                             \
                asm volatile("s_waitcnt vmcnt(4)" ::: "memory");               \
            } else {                                                           \
                asm volatile("s_waitcnt vmcnt(16)" ::: "memory");              \
            }                                                                  \
            __builtin_amdgcn_s_barrier();                                      \
            __builtin_amdgcn_sched_barrier(0);                                 \
        }                                                                      \
    }

#define QKV_RUN(BASE)                                                          \
    {                                                                          \
        const int s_end = (BASE) + 12;                                         \
        asm volatile("s_waitcnt vmcnt(0)" ::: "memory");                       \
        __builtin_amdgcn_s_barrier();                                          \
        __builtin_amdgcn_sched_barrier(0);                                     \
        _Pragma("unroll")                                                      \
        for (int ss = 0; ss < 12; ++ss) { QKV_STEP((BASE) + ss, ss & 1); }     \
    }

    if (half == 0) { QKV_RUN(0); } else { QKV_RUN(12); }
#undef QKV_RUN
#undef QKV_STEP
#undef STW
}

// ---------------------------------------------------------------------------
// k_attn (fused attn + Wo proj + SEGMENT-MEAN). R12 structure; phase-2
// epilogue now atomically accumulates s[m]*acc directly into d_out
// (s[m] = mask^2 * inv_cnt[uid[m]], 32 per-block values staged in a dead
// corner of Qs). OUT buffer and k_seg are gone. LDS exactly 80 KB -> 2/CU.
// ---------------------------------------------------------------------------
__global__ __launch_bounds__(512, 2) void k_attn(const f16* __restrict__ Qo,
                                                 const f16* __restrict__ Ko,
                                                 const f16* __restrict__ VW,
                                                 const f16* __restrict__ Wsw,
                                                 const int* __restrict__ uid,
                                                 const float* __restrict__ mask,
                                                 const float* __restrict__ inv,
                                                 float* __restrict__ fout) {
    __shared__ f16 Ks[128 * 256];   // 64 KB (AOs overlays part of it later)
    __shared__ f16 Qs[32 * 256];    // 16 KB (head reused for s/t tables late)

    const int tid  = threadIdx.x;
    const int idx  = blockIdx.x;
    const int lin  = (idx & 7) * 128 + (idx >> 3);   // contiguous (b,c) per XCD
    const int b    = lin >> 9;
    const int c    = lin & 511;
    const int h    = tid >> 6;
    const int l31  = tid & 31;
    const int hi   = (tid & 63) >> 5;

    const int u0 = 32 * c - 48;
    const int e0 = (32 * c + 80 < Mg) ? (32 * c + 80) : Mg;
    const bool full = (u0 >= 0) && (32 * c + 80 <= Mg);

    // ---- stage K window: 8 coalesced gll16 / thread
    const f16* Kb = Ko + (size_t)b * Mg * 256;
#pragma unroll
    for (int i = 0; i < 8; ++i) {
        int g = i * 512 + tid;
        int r = g >> 5, s = g & 31;
        int m = u0 + r;
        m = m < 0 ? 0 : (m > Mg - 1 ? Mg - 1 : m);
        gll16(Kb + (size_t)m * 256 + ((s ^ (r & 31)) << 3), &Ks[g * 8]);
    }
    // ---- stage Q tile: 2 coalesced gll16 / thread
    const f16* Qb = Qo + ((size_t)b * Mg + 32 * c) * 256;
#pragma unroll
    for (int i = 0; i < 2; ++i) {
        int g = i * 512 + tid;
        int r = g >> 5, s = g & 31;
        gll16(Qb + (size_t)r * 256 + ((s ^ r) << 3), &Qs[g * 8]);
    }
    __syncthreads();

    // ---- V loads direct to registers, issued early
    const f16* Vbb = VW + (size_t)b * 2048 * 256 * 8;
    f16x4 v0r[8], v1r[8];
#pragma unroll
    for (int s = 0; s < 8; ++s) {
        int g0 = (u0 >> 3) + 2 * s;
        int g1 = g0 + 1;
        g0 = g0 < 0 ? 0 : (g0 > 2047 ? 2047 : g0);
        g1 = g1 < 0 ? 0 : (g1 > 2047 ? 2047 : g1);
        v0r[s] = *(const f16x4*)(Vbb + ((size_t)g0 * 256 + 32 * h + l31) * 8 + 4 * hi);
        v1r[s] = *(const f16x4*)(Vbb + ((size_t)g1 * 256 + 32 * h + l31) * 8 + 4 * hi);
    }

    // ---- Q fragments from LDS (key = row = l31)
    f16x8 qf0 = *(const f16x8*)&Qs[l31 * 256 + (((4 * h + hi) ^ l31) << 3)];
    f16x8 qf1 = *(const f16x8*)&Qs[l31 * 256 + (((4 * h + 2 + hi) ^ l31) << 3)];

    // ---- QK^T from LDS
    f32x16 p4[4];
#pragma unroll
    for (int t = 0; t < 4; ++t)
#pragma unroll
        for (int e = 0; e < 16; ++e) p4[t][e] = 0.f;

    __builtin_amdgcn_s_setprio(1);
#pragma unroll
    for (int t = 0; t < 4; ++t) {
        int rr = 32 * t + l31;
        f16x8 kf0 = *(const f16x8*)&Ks[rr * 256 + (((4 * h + hi) ^ l31) << 3)];
        f16x8 kf1 = *(const f16x8*)&Ks[rr * 256 + (((4 * h + 2 + hi) ^ l31) << 3)];
        p4[t] = MFMA(kf0, qf0, p4[t]);
        p4[t] = MFMA(kf1, qf1, p4[t]);
    }
    __builtin_amdgcn_s_setprio(0);

    // ---- in-register softmax (scores already in log2 domain)
    float mx = -3e38f;
    float sum = 0.f;
    if (full) {
#pragma unroll
        for (int t = 0; t < 4; ++t)
#pragma unroll
            for (int r = 0; r < 16; ++r) mx = fmaxf(mx, p4[t][r]);
        mx = fmaxf(mx, __shfl_xor(mx, 32));
#pragma unroll
        for (int t = 0; t < 4; ++t)
#pragma unroll
            for (int r = 0; r < 16; ++r) {
                float ev = exp2f(p4[t][r] - mx);
                p4[t][r] = ev;
                sum += ev;
            }
    } else {
#pragma unroll
        for (int t = 0; t < 4; ++t)
#pragma unroll
            for (int r = 0; r < 16; ++r) {
                int gm = u0 + 32 * t + (r & 3) + 8 * (r >> 2) + 4 * hi;
                if (gm >= 0 && gm < e0) mx = fmaxf(mx, p4[t][r]);
            }
        mx = fmaxf(mx, __shfl_xor(mx, 32));
#pragma unroll
        for (int t = 0; t < 4; ++t)
#pragma unroll
            for (int r = 0; r < 16; ++r) {
                int gm = u0 + 32 * t + (r & 3) + 8 * (r >> 2) + 4 * hi;
                float ev = (gm >= 0 && gm < e0) ? exp2f(p4[t][r] - mx) : 0.f;
                p4[t][r] = ev;
                sum += ev;
            }
    }
    sum += __shfl_xor(sum, 32);
    const float invs = 1.f / sum;
#pragma unroll
    for (int t = 0; t < 4; ++t)
#pragma unroll
        for (int e = 0; e < 16; ++e) p4[t][e] *= invs;

    // ---- PV (all-register; V loads drained here)
    asm volatile("s_waitcnt vmcnt(0)" ::: "memory");
    __builtin_amdgcn_sched_barrier(0);

    f32x16 o;
#pragma unroll
    for (int e = 0; e < 16; ++e) o[e] = 0.f;

    __builtin_amdgcn_s_setprio(1);
#pragma unroll
    for (int s = 0; s < 8; ++s) {
        f16x8 pa;
#pragma unroll
        for (int e = 0; e < 8; ++e) pa[e] = (f16)(p4[s >> 1][8 * (s & 1) + e]);
        o = MFMA(pa, mk8(v0r[s], v1r[s]), o);
    }
    __builtin_amdgcn_s_setprio(0);

    // ---- AOs overlays K LDS; s/t tables into Qs head (both dead now)
    __syncthreads();
    {
        const int col = h * 32 + l31;
#pragma unroll
        for (int r = 0; r < 16; ++r) {
            int row = (r & 3) + 8 * (r >> 2) + 4 * hi;
            Ks[row * 264 + col] = (f16)o[r];
        }
    }
    if (tid < 32) {
        int m = 32 * c + tid;
        int t = uid[b * Mg + m];
        float msk = mask[b * Mg + m];
        *reinterpret_cast<float*>(&Qs[2 * tid])      = msk * msk * inv[b * 2048 + t];
        *reinterpret_cast<int*>(&Qs[64 + 2 * tid])   = t;
    }
    __syncthreads();

    // ---- phase 2: atomically accumulate (AO x Wo) * s[m] into fout[b][t][:]
    {
        const f16* Wb = Wsw + 3 * 65536;
        f32x16 acc;
#pragma unroll
        for (int e = 0; e < 16; ++e) acc[e] = 0.f;
        __builtin_amdgcn_s_setprio(1);
#pragma unroll
        for (int g = 0; g < 16; ++g) {
            int gp = 2 * g + hi;
            f16x8 av = *(const f16x8*)&Ks[l31 * 264 + gp * 8];
            f16x8 bv = *(const f16x8*)(Wb + ((size_t)gp * 256 + 32 * h + l31) * 8);
            acc = MFMA(av, bv, acc);
        }
        __builtin_amdgcn_s_setprio(0);
#pragma unroll
        for (int r = 0; r < 16; ++r) {
            int row = (r & 3) + 8 * (r >> 2) + 4 * hi;
            float s = *reinterpret_cast<const float*>(&Qs[2 * row]);
            int   t = *reinterpret_cast<const int*>(&Qs[64 + 2 * row]);
            atomicAdd(&fout[((size_t)b * Ntok + t) * 256 + h * 32 + l31], acc[r] * s);
        }
    }
}

// ---------------------------------------------------------------------------
extern "C" void kernel_launch(void* const* d_in, const int* in_sizes, int n_in,
                              void* d_out, int out_size, void* d_ws, size_t ws_size,
                              hipStream_t stream) {
    const float* f_atom = (const float*)d_in[0];
    const float* amask  = (const float*)d_in[1];
    const float* Wq     = (const float*)d_in[2];
    const float* Wk     = (const float*)d_in[3];
    const float* Wv     = (const float*)d_in[4];
    const float* Wo     = (const float*)d_in[5];
    const int*   uid    = (const int*)d_in[6];

    const size_t HALF_WT  = 4 * 65536;
    const size_t HALF_MAT = (size_t)Bg * Mg * Dg;
    const size_t needed_bytes = (HALF_WT + 3 * HALF_MAT) * sizeof(f16) + 2 * 2048 * sizeof(float);
    if (ws_size < needed_bytes) return;

    f16* Wsw  = (f16*)d_ws;
    f16* Qb   = Wsw + HALF_WT;
    f16* Kb   = Qb + HALF_MAT;
    f16* VWb  = Kb + HALF_MAT;
    float* inv = (float*)(VWb + HALF_MAT);

    // d_out is poisoned (0xAA) by the harness; zero it for atomic accumulation
    hipMemsetAsync(d_out, 0, (size_t)out_size * sizeof(float), stream);

    k_wt  <<<dim3(1024), 256, 0, stream>>>(Wq, Wk, Wv, Wo, uid, amask, Wsw, inv);
    k_qkv <<<dim3(512), 256, 0, stream>>>(f_atom, Wsw, Qb, Kb, VWb);
    k_attn<<<dim3(1024), 512, 0, stream>>>(Qb, Kb, VWb, Wsw, uid, amask, inv,
                                           (float*)d_out);
}

// Round 16
// 76.977 us; speedup vs baseline: 1.5235x; 1.5235x over previous
//
#include <hip/hip_runtime.h>

typedef _Float16 f16;
typedef _Float16 f16x4 __attribute__((ext_vector_type(4)));
typedef _Float16 f16x8 __attribute__((ext_vector_type(8)));
typedef float    f32x16 __attribute__((ext_vector_type(16)));

#define MFMA(a, b, c) __builtin_amdgcn_mfma_f32_32x32x16_f16((a), (b), (c), 0, 0, 0)

static constexpr int Mg   = 16384;
static constexpr int Bg   = 2;
static constexpr int Dg   = 256;
static constexpr int Hg   = 8;
static constexpr int Cg   = 512;
static constexpr int Ntok = 2048;
// 1/sqrt(32) * log2(e): k_attn softmax uses exp2f directly
static constexpr float QSCALE = 0.25503487f;

typedef __attribute__((address_space(1))) const void gbl_cv;
typedef __attribute__((address_space(3))) void lds_v;

static __device__ __forceinline__ void gll16(const f16* g, f16* l) {
    __builtin_amdgcn_global_load_lds((gbl_cv*)g, (lds_v*)l, 16, 0, 0);
}
static __device__ __forceinline__ f16x8 mk8(f16x4 a, f16x4 b) {
    f16x8 r;
    r[0] = a[0]; r[1] = a[1]; r[2] = a[2]; r[3] = a[3];
    r[4] = b[0]; r[5] = b[1]; r[6] = b[2]; r[7] = b[3];
    return r;
}

// ---------------------------------------------------------------------------
// k_wt: W[k][n] fp32 -> fp16.
//   w<3 (Wq,Wk,Wv):  Wsw[w][n][granule (k>>3)^(n&7)]  (k_qkv staging layout)
//   w==3 (Wo):       Wsw[3][(k>>3)][n][k&7]           (granule-major)
// First 4098 threads also binary-search token boundaries for k_seg.
// ---------------------------------------------------------------------------
__global__ __launch_bounds__(256) void k_wt(const float* __restrict__ Wq,
                                            const float* __restrict__ Wk,
                                            const float* __restrict__ Wv,
                                            const float* __restrict__ Wo,
                                            const int* __restrict__ uid,
                                            f16* __restrict__ Wsw,
                                            int* __restrict__ starts) {
    int idx = blockIdx.x * 256 + threadIdx.x;
    int w   = idx >> 16;
    int rem = idx & 65535;
    int k   = rem >> 8;
    int n   = rem & 255;
    if (w < 3) {
        const float* W = (w == 0) ? Wq : (w == 1) ? Wk : Wv;
        int G = (k >> 3) ^ (n & 7);
        Wsw[w * 65536 + n * 256 + (G << 3) + (k & 7)] = (f16)W[k * 256 + n];
    } else {
        Wsw[3 * 65536 + ((k >> 3) * 256 + n) * 8 + (k & 7)] = (f16)Wo[k * 256 + n];
    }
    if (idx < 2 * 2049) {
        int b = idx / 2049, t = idx % 2049;
        const int* u = uid + b * Mg;
        int lo = 0, hi = Mg;
        while (lo < hi) { int mid = (lo + hi) >> 1; if (u[mid] < t) lo = mid + 1; else hi = mid; }
        starts[idx] = lo;
    }
}

// ---------------------------------------------------------------------------
// k_qkv: A-in-registers GEMM (validated R9/R12 — best measured). 512 blocks,
// 4 waves, 12 steps. First W-tile stage issued BEFORE the A-register loads.
// V written granule-major VW[b][m>>3][d][m&7].
// R13 lesson: 512-thr/(,4) variant spills a[16] — keep 256 thr / (,2).
// ---------------------------------------------------------------------------
__global__ __launch_bounds__(256, 2) void k_qkv(const float* __restrict__ A,
                                                const f16* __restrict__ Wsw,
                                                f16* __restrict__ Qo,
                                                f16* __restrict__ Ko,
                                                f16* __restrict__ VW) {
    __shared__ f16 Ls[2][32 * 256];   // 2 x 16 KB

    const int tid  = threadIdx.x;
    const int d    = blockIdx.x;
    const int lin  = (d & 7) * 64 + (d >> 3);
    const int yt   = lin >> 1;
    const int half = lin & 1;
    const int m0   = yt * 128;
    const int lane = tid & 63, w = tid >> 6;
    const int l31  = lane & 31, hi = lane >> 5;
    const int mrow = m0 + 32 * w + l31;
    const int xr   = l31 & 7;

#define STW(S, BB)                                                             \
    {                                                                          \
        const f16* src = Wsw + ((S) >> 3) * 65536 + (((S) & 7) * 32) * 256;    \
        _Pragma("unroll")                                                      \
        for (int i = 0; i < 4; ++i) {                                          \
            int g2 = i * 256 + tid;                                            \
            gll16(src + g2 * 8, &Ls[BB][g2 * 8]);                              \
        }                                                                      \
    }

    // ---- issue first W stage, then A loads (stage latency hides under A)
    if (half == 0) { STW(0, 0); } else { STW(12, 0); }

    f16x8 a[16];
    const float* ap = A + (size_t)mrow * 256 + 8 * hi;
#pragma unroll
    for (int g = 0; g < 16; ++g) {
        float4 v0 = *reinterpret_cast<const float4*>(ap + 16 * g);
        float4 v1 = *reinterpret_cast<const float4*>(ap + 16 * g + 4);
        f16x8 t;
        t[0] = (f16)v0.x; t[1] = (f16)v0.y; t[2] = (f16)v0.z; t[3] = (f16)v0.w;
        t[4] = (f16)v1.x; t[5] = (f16)v1.y; t[6] = (f16)v1.z; t[7] = (f16)v1.w;
        a[g] = t;
    }

#define QKV_STEP(S, BB)                                                        \
    {                                                                          \
        if ((S) + 1 < s_end) { STW((S) + 1, (BB) ^ 1); }                       \
        f32x16 acc;                                                            \
        _Pragma("unroll")                                                      \
        for (int e = 0; e < 16; ++e) acc[e] = 0.f;                             \
        _Pragma("unroll")                                                      \
        for (int g = 0; g < 16; ++g) {                                         \
            f16x8 bf = *(const f16x8*)&Ls[BB][l31 * 256 +                      \
                                             (((2 * g + hi) ^ xr) << 3)];      \
            acc = MFMA(a[g], bf, acc);                                         \
        }                                                                      \
        const int wix  = (S) >> 3;                                             \
        const int gcol = ((S) & 7) * 32 + l31;                                 \
        const int mb   = m0 + 32 * w + 4 * hi;                                 \
        if (wix == 0) {                                                        \
            _Pragma("unroll")                                                  \
            for (int r = 0; r < 16; ++r)                                       \
                Qo[(size_t)(mb + (r & 3) + 8 * (r >> 2)) * 256 + gcol] =       \
                    (f16)(acc[r] * QSCALE);                                    \
        } else if (wix == 1) {                                                 \
            _Pragma("unroll")                                                  \
            for (int r = 0; r < 16; ++r)                                       \
                Ko[(size_t)(mb + (r & 3) + 8 * (r >> 2)) * 256 + gcol] =       \
                    (f16)acc[r];                                               \
        } else {                                                               \
            _Pragma("unroll")                                                  \
            for (int rq = 0; rq < 4; ++rq) {                                   \
                f16x4 pv = { (f16)acc[rq * 4 + 0], (f16)acc[rq * 4 + 1],       \
                             (f16)acc[rq * 4 + 2], (f16)acc[rq * 4 + 3] };     \
                int mr  = mb + 8 * rq;                                         \
                int bb2 = mr >> 14;                                            \
                int msg = (mr & 16383) >> 3;                                   \
                *reinterpret_cast<f16x4*>(VW + ((size_t)(bb2 * 2048 + msg) *   \
                                          256 + gcol) * 8 + 4 * hi) = pv;      \
            }                                                                  \
        }                                                                      \
        if ((S) + 1 < s_end) {                                                 \
            if (((S) >> 3) == 2) {                                             \
                asm volatile("s_waitcnt vmcnt(4)" ::: "memory");               \
            } else {                                                           \
                asm volatile("s_waitcnt vmcnt(16)" ::: "memory");              \
            }                                                                  \
            __builtin_amdgcn_s_barrier();                                      \
            __builtin_amdgcn_sched_barrier(0);                                 \
        }                                                                      \
    }

#define QKV_RUN(BASE)                                                          \
    {                                                                          \
        const int s_end = (BASE) + 12;                                         \
        asm volatile("s_waitcnt vmcnt(0)" ::: "memory");                       \
        __builtin_amdgcn_s_barrier();                                          \
        __builtin_amdgcn_sched_barrier(0);                                     \
        _Pragma("unroll")                                                      \
        for (int ss = 0; ss < 12; ++ss) { QKV_STEP((BASE) + ss, ss & 1); }     \
    }

    if (half == 0) { QKV_RUN(0); } else { QKV_RUN(12); }
#undef QKV_RUN
#undef QKV_STEP
#undef STW
}

// ---------------------------------------------------------------------------
// k_attn (fused attn + Wo proj; exact R9/R12 structure — best measured).
// exp2f softmax (log2e folded into QSCALE upstream). LDS 80 KB -> 2 blk/CU.
// ---------------------------------------------------------------------------
__global__ __launch_bounds__(512, 2) void k_attn(const f16* __restrict__ Qo,
                                                 const f16* __restrict__ Ko,
                                                 const f16* __restrict__ VW,
                                                 const f16* __restrict__ Wsw,
                                                 f16* __restrict__ OUT) {
    __shared__ f16 Ks[128 * 256];   // 64 KB (AOs overlays part of it later)
    __shared__ f16 Qs[32 * 256];    // 16 KB

    const int tid  = threadIdx.x;
    const int idx  = blockIdx.x;
    const int lin  = (idx & 7) * 128 + (idx >> 3);   // contiguous (b,c) per XCD
    const int b    = lin >> 9;
    const int c    = lin & 511;
    const int h    = tid >> 6;
    const int l31  = tid & 31;
    const int hi   = (tid & 63) >> 5;

    const int u0 = 32 * c - 48;
    const int e0 = (32 * c + 80 < Mg) ? (32 * c + 80) : Mg;
    const bool full = (u0 >= 0) && (32 * c + 80 <= Mg);

    // ---- stage K window: 8 coalesced gll16 / thread
    const f16* Kb = Ko + (size_t)b * Mg * 256;
#pragma unroll
    for (int i = 0; i < 8; ++i) {
        int g = i * 512 + tid;
        int r = g >> 5, s = g & 31;
        int m = u0 + r;
        m = m < 0 ? 0 : (m > Mg - 1 ? Mg - 1 : m);
        gll16(Kb + (size_t)m * 256 + ((s ^ (r & 31)) << 3), &Ks[g * 8]);
    }
    // ---- stage Q tile: 2 coalesced gll16 / thread
    const f16* Qb = Qo + ((size_t)b * Mg + 32 * c) * 256;
#pragma unroll
    for (int i = 0; i < 2; ++i) {
        int g = i * 512 + tid;
        int r = g >> 5, s = g & 31;
        gll16(Qb + (size_t)r * 256 + ((s ^ r) << 3), &Qs[g * 8]);
    }
    __syncthreads();

    // ---- V loads direct to registers, issued early
    const f16* Vbb = VW + (size_t)b * 2048 * 256 * 8;
    f16x4 v0r[8], v1r[8];
#pragma unroll
    for (int s = 0; s < 8; ++s) {
        int g0 = (u0 >> 3) + 2 * s;
        int g1 = g0 + 1;
        g0 = g0 < 0 ? 0 : (g0 > 2047 ? 2047 : g0);
        g1 = g1 < 0 ? 0 : (g1 > 2047 ? 2047 : g1);
        v0r[s] = *(const f16x4*)(Vbb + ((size_t)g0 * 256 + 32 * h + l31) * 8 + 4 * hi);
        v1r[s] = *(const f16x4*)(Vbb + ((size_t)g1 * 256 + 32 * h + l31) * 8 + 4 * hi);
    }

    // ---- Q fragments from LDS (key = row = l31)
    f16x8 qf0 = *(const f16x8*)&Qs[l31 * 256 + (((4 * h + hi) ^ l31) << 3)];
    f16x8 qf1 = *(const f16x8*)&Qs[l31 * 256 + (((4 * h + 2 + hi) ^ l31) << 3)];

    // ---- QK^T from LDS
    f32x16 p4[4];
#pragma unroll
    for (int t = 0; t < 4; ++t)
#pragma unroll
        for (int e = 0; e < 16; ++e) p4[t][e] = 0.f;

    __builtin_amdgcn_s_setprio(1);
#pragma unroll
    for (int t = 0; t < 4; ++t) {
        int rr = 32 * t + l31;
        f16x8 kf0 = *(const f16x8*)&Ks[rr * 256 + (((4 * h + hi) ^ l31) << 3)];
        f16x8 kf1 = *(const f16x8*)&Ks[rr * 256 + (((4 * h + 2 + hi) ^ l31) << 3)];
        p4[t] = MFMA(kf0, qf0, p4[t]);
        p4[t] = MFMA(kf1, qf1, p4[t]);
    }
    __builtin_amdgcn_s_setprio(0);

    // ---- in-register softmax (scores already in log2 domain)
    float mx = -3e38f;
    float sum = 0.f;
    if (full) {
#pragma unroll
        for (int t = 0; t < 4; ++t)
#pragma unroll
            for (int r = 0; r < 16; ++r) mx = fmaxf(mx, p4[t][r]);
        mx = fmaxf(mx, __shfl_xor(mx, 32));
#pragma unroll
        for (int t = 0; t < 4; ++t)
#pragma unroll
            for (int r = 0; r < 16; ++r) {
                float ev = exp2f(p4[t][r] - mx);
                p4[t][r] = ev;
                sum += ev;
            }
    } else {
#pragma unroll
        for (int t = 0; t < 4; ++t)
#pragma unroll
            for (int r = 0; r < 16; ++r) {
                int gm = u0 + 32 * t + (r & 3) + 8 * (r >> 2) + 4 * hi;
                if (gm >= 0 && gm < e0) mx = fmaxf(mx, p4[t][r]);
            }
        mx = fmaxf(mx, __shfl_xor(mx, 32));
#pragma unroll
        for (int t = 0; t < 4; ++t)
#pragma unroll
            for (int r = 0; r < 16; ++r) {
                int gm = u0 + 32 * t + (r & 3) + 8 * (r >> 2) + 4 * hi;
                float ev = (gm >= 0 && gm < e0) ? exp2f(p4[t][r] - mx) : 0.f;
                p4[t][r] = ev;
                sum += ev;
            }
    }
    sum += __shfl_xor(sum, 32);
    const float inv = 1.f / sum;
#pragma unroll
    for (int t = 0; t < 4; ++t)
#pragma unroll
        for (int e = 0; e < 16; ++e) p4[t][e] *= inv;

    // ---- PV (all-register; V loads drained here)
    asm volatile("s_waitcnt vmcnt(0)" ::: "memory");
    __builtin_amdgcn_sched_barrier(0);

    f32x16 o;
#pragma unroll
    for (int e = 0; e < 16; ++e) o[e] = 0.f;

    __builtin_amdgcn_s_setprio(1);
#pragma unroll
    for (int s = 0; s < 8; ++s) {
        f16x8 pa;
#pragma unroll
        for (int e = 0; e < 8; ++e) pa[e] = (f16)(p4[s >> 1][8 * (s & 1) + e]);
        o = MFMA(pa, mk8(v0r[s], v1r[s]), o);
    }
    __builtin_amdgcn_s_setprio(0);

    // ---- AOs overlays K LDS (QK^T reads done after this barrier)
    __syncthreads();
    {
        const int col = h * 32 + l31;
#pragma unroll
        for (int r = 0; r < 16; ++r) {
            int row = (r & 3) + 8 * (r >> 2) + 4 * hi;
            Ks[row * 264 + col] = (f16)o[r];
        }
    }
    __syncthreads();

    // ---- phase 2: OUT[:, 32h..32h+31] = AO x Wo
    {
        const f16* Wb = Wsw + 3 * 65536;
        f32x16 acc;
#pragma unroll
        for (int e = 0; e < 16; ++e) acc[e] = 0.f;
        __builtin_amdgcn_s_setprio(1);
#pragma unroll
        for (int g = 0; g < 16; ++g) {
            int gp = 2 * g + hi;
            f16x8 av = *(const f16x8*)&Ks[l31 * 264 + gp * 8];
            f16x8 bv = *(const f16x8*)(Wb + ((size_t)gp * 256 + 32 * h + l31) * 8);
            acc = MFMA(av, bv, acc);
        }
        __builtin_amdgcn_s_setprio(0);
#pragma unroll
        for (int r = 0; r < 16; ++r) {
            int row = (r & 3) + 8 * (r >> 2) + 4 * hi;
            OUT[((size_t)b * Mg + 32 * c + row) * 256 + h * 32 + l31] = (f16)acc[r];
        }
    }
}

// ---------------------------------------------------------------------------
// k_seg: segment mean per (token, batch), boundaries precomputed in k_wt.
// grid (2048, 2), block 256. (ref applies mask twice -> msk^2 weighting)
// ---------------------------------------------------------------------------
__global__ __launch_bounds__(256) void k_seg(const f16* __restrict__ OUT,
                                             const int* __restrict__ starts,
                                             const float* __restrict__ mask,
                                             float* __restrict__ out) {
    const int t = blockIdx.x, b = blockIdx.y;
    const int d = threadIdx.x;

    const int lo  = starts[b * 2049 + t];
    const int lo2 = starts[b * 2049 + t + 1];

    float sum = 0.f, cnt = 0.f;
    for (int m = lo; m < lo2; ++m) {
        float msk = mask[b * Mg + m];
        sum += msk * msk * (float)OUT[((size_t)b * Mg + m) * 256 + d];
        cnt += msk;
    }
    out[((size_t)b * Ntok + t) * 256 + d] = sum / (cnt + 1e-8f);
}

// ---------------------------------------------------------------------------
extern "C" void kernel_launch(void* const* d_in, const int* in_sizes, int n_in,
                              void* d_out, int out_size, void* d_ws, size_t ws_size,
                              hipStream_t stream) {
    const float* f_atom = (const float*)d_in[0];
    const float* amask  = (const float*)d_in[1];
    const float* Wq     = (const float*)d_in[2];
    const float* Wk     = (const float*)d_in[3];
    const float* Wv     = (const float*)d_in[4];
    const float* Wo     = (const float*)d_in[5];
    const int*   uid    = (const int*)d_in[6];

    const size_t HALF_WT  = 4 * 65536;
    const size_t HALF_MAT = (size_t)Bg * Mg * Dg;
    const size_t needed_bytes = (HALF_WT + 4 * HALF_MAT) * sizeof(f16) + 2 * 2049 * sizeof(int);
    if (ws_size < needed_bytes) return;

    f16* Wsw  = (f16*)d_ws;
    f16* Qb   = Wsw + HALF_WT;
    f16* Kb   = Qb + HALF_MAT;
    f16* VWb  = Kb + HALF_MAT;
    f16* OUTb = VWb + HALF_MAT;
    int* starts = (int*)(OUTb + HALF_MAT);

    k_wt  <<<dim3(1024), 256, 0, stream>>>(Wq, Wk, Wv, Wo, uid, Wsw, starts);
    k_qkv <<<dim3(512), 256, 0, stream>>>(f_atom, Wsw, Qb, Kb, VWb);
    k_attn<<<dim3(1024), 512, 0, stream>>>(Qb, Kb, VWb, Wsw, OUTb);
    k_seg <<<dim3(Ntok, Bg), 256, 0, stream>>>(OUTb, starts, amask, (float*)d_out);
}

// Round 17
// 73.833 us; speedup vs baseline: 1.5884x; 1.0426x over previous
//
#include <hip/hip_runtime.h>

typedef _Float16 f16;
typedef _Float16 f16x4 __attribute__((ext_vector_type(4)));
typedef _Float16 f16x8 __attribute__((ext_vector_type(8)));
typedef float    f32x16 __attribute__((ext_vector_type(16)));

#define MFMA(a, b, c) __builtin_amdgcn_mfma_f32_32x32x16_f16((a), (b), (c), 0, 0, 0)

static constexpr int Mg   = 16384;
static constexpr int Bg   = 2;
static constexpr int Dg   = 256;
static constexpr int Hg   = 8;
static constexpr int Cg   = 512;
static constexpr int Ntok = 2048;
// 1/sqrt(32) * log2(e): k_attn softmax uses exp2f directly
static constexpr float QSCALE = 0.25503487f;

typedef __attribute__((address_space(1))) const void gbl_cv;
typedef __attribute__((address_space(3))) void lds_v;

static __device__ __forceinline__ void gll16(const f16* g, f16* l) {
    __builtin_amdgcn_global_load_lds((gbl_cv*)g, (lds_v*)l, 16, 0, 0);
}
static __device__ __forceinline__ f16x8 mk8(f16x4 a, f16x4 b) {
    f16x8 r;
    r[0] = a[0]; r[1] = a[1]; r[2] = a[2]; r[3] = a[3];
    r[4] = b[0]; r[5] = b[1]; r[6] = b[2]; r[7] = b[3];
    return r;
}

// ---------------------------------------------------------------------------
// k_wt: W[k][n] fp32 -> fp16.
//   w<3 (Wq,Wk,Wv):  Wsw[w][n][granule (k>>3)^(n&7)]  (k_qkv staging layout)
//   w==3 (Wo):       Wsw[3][(k>>3)][n][k&7]           (granule-major)
// First 4098 threads also binary-search token boundaries for k_seg.
// ---------------------------------------------------------------------------
__global__ __launch_bounds__(256) void k_wt(const float* __restrict__ Wq,
                                            const float* __restrict__ Wk,
                                            const float* __restrict__ Wv,
                                            const float* __restrict__ Wo,
                                            const int* __restrict__ uid,
                                            f16* __restrict__ Wsw,
                                            int* __restrict__ starts) {
    int idx = blockIdx.x * 256 + threadIdx.x;
    int w   = idx >> 16;
    int rem = idx & 65535;
    int k   = rem >> 8;
    int n   = rem & 255;
    if (w < 3) {
        const float* W = (w == 0) ? Wq : (w == 1) ? Wk : Wv;
        int G = (k >> 3) ^ (n & 7);
        Wsw[w * 65536 + n * 256 + (G << 3) + (k & 7)] = (f16)W[k * 256 + n];
    } else {
        Wsw[3 * 65536 + ((k >> 3) * 256 + n) * 8 + (k & 7)] = (f16)Wo[k * 256 + n];
    }
    if (idx < 2 * 2049) {
        int b = idx / 2049, t = idx % 2049;
        const int* u = uid + b * Mg;
        int lo = 0, hi = Mg;
        while (lo < hi) { int mid = (lo + hi) >> 1; if (u[mid] < t) lo = mid + 1; else hi = mid; }
        starts[idx] = lo;
    }
}

// ---------------------------------------------------------------------------
// k_qkv: A-in-registers GEMM (validated R9/R12 — best measured). 512 blocks,
// 4 waves, 12 steps. First W-tile stage issued BEFORE the A-register loads.
// V written granule-major VW[b][m>>3][d][m&7].
// R13 lesson: 512-thr/(,4) variant spills a[16] — keep 256 thr / (,2).
// ---------------------------------------------------------------------------
__global__ __launch_bounds__(256, 2) void k_qkv(const float* __restrict__ A,
                                                const f16* __restrict__ Wsw,
                                                f16* __restrict__ Qo,
                                                f16* __restrict__ Ko,
                                                f16* __restrict__ VW) {
    __shared__ f16 Ls[2][32 * 256];   // 2 x 16 KB

    const int tid  = threadIdx.x;
    const int d    = blockIdx.x;
    const int lin  = (d & 7) * 64 + (d >> 3);
    const int yt   = lin >> 1;
    const int half = lin & 1;
    const int m0   = yt * 128;
    const int lane = tid & 63, w = tid >> 6;
    const int l31  = lane & 31, hi = lane >> 5;
    const int mrow = m0 + 32 * w + l31;
    const int xr   = l31 & 7;

#define STW(S, BB)                                                             \
    {                                                                          \
        const f16* src = Wsw + ((S) >> 3) * 65536 + (((S) & 7) * 32) * 256;    \
        _Pragma("unroll")                                                      \
        for (int i = 0; i < 4; ++i) {                                          \
            int g2 = i * 256 + tid;                                            \
            gll16(src + g2 * 8, &Ls[BB][g2 * 8]);                              \
        }                                                                      \
    }

    // ---- issue first W stage, then A loads (stage latency hides under A)
    if (half == 0) { STW(0, 0); } else { STW(12, 0); }

    f16x8 a[16];
    const float* ap = A + (size_t)mrow * 256 + 8 * hi;
#pragma unroll
    for (int g = 0; g < 16; ++g) {
        float4 v0 = *reinterpret_cast<const float4*>(ap + 16 * g);
        float4 v1 = *reinterpret_cast<const float4*>(ap + 16 * g + 4);
        f16x8 t;
        t[0] = (f16)v0.x; t[1] = (f16)v0.y; t[2] = (f16)v0.z; t[3] = (f16)v0.w;
        t[4] = (f16)v1.x; t[5] = (f16)v1.y; t[6] = (f16)v1.z; t[7] = (f16)v1.w;
        a[g] = t;
    }

#define QKV_STEP(S, BB)                                                        \
    {                                                                          \
        if ((S) + 1 < s_end) { STW((S) + 1, (BB) ^ 1); }                       \
        f32x16 acc;                                                            \
        _Pragma("unroll")                                                      \
        for (int e = 0; e < 16; ++e) acc[e] = 0.f;                             \
        _Pragma("unroll")                                                      \
        for (int g = 0; g < 16; ++g) {                                         \
            f16x8 bf = *(const f16x8*)&Ls[BB][l31 * 256 +                      \
                                             (((2 * g + hi) ^ xr) << 3)];      \
            acc = MFMA(a[g], bf, acc);                                         \
        }                                                                      \
        const int wix  = (S) >> 3;                                             \
        const int gcol = ((S) & 7) * 32 + l31;                                 \
        const int mb   = m0 + 32 * w + 4 * hi;                                 \
        if (wix == 0) {                                                        \
            _Pragma("unroll")                                                  \
            for (int r = 0; r < 16; ++r)                                       \
                Qo[(size_t)(mb + (r & 3) + 8 * (r >> 2)) * 256 + gcol] =       \
                    (f16)(acc[r] * QSCALE);                                    \
        } else if (wix == 1) {                                                 \
            _Pragma("unroll")                                                  \
            for (int r = 0; r < 16; ++r)                                       \
                Ko[(size_t)(mb + (r & 3) + 8 * (r >> 2)) * 256 + gcol] =       \
                    (f16)acc[r];                                               \
        } else {                                                               \
            _Pragma("unroll")                                                  \
            for (int rq = 0; rq < 4; ++rq) {                                   \
                f16x4 pv = { (f16)acc[rq * 4 + 0], (f16)acc[rq * 4 + 1],       \
                             (f16)acc[rq * 4 + 2], (f16)acc[rq * 4 + 3] };     \
                int mr  = mb + 8 * rq;                                         \
                int bb2 = mr >> 14;                                            \
                int msg = (mr & 16383) >> 3;                                   \
                *reinterpret_cast<f16x4*>(VW + ((size_t)(bb2 * 2048 + msg) *   \
                                          256 + gcol) * 8 + 4 * hi) = pv;      \
            }                                                                  \
        }                                                                      \
        if ((S) + 1 < s_end) {                                                 \
            if (((S) >> 3) == 2) {                                             \
                asm volatile("s_waitcnt vmcnt(4)" ::: "memory");               \
            } else {                                                           \
                asm volatile("s_waitcnt vmcnt(16)" ::: "memory");              \
            }                                                                  \
            __builtin_amdgcn_s_barrier();                                      \
            __builtin_amdgcn_sched_barrier(0);                                 \
        }                                                                      \
    }

#define QKV_RUN(BASE)                                                          \
    {                                                                          \
        const int s_end = (BASE) + 12;                                         \
        asm volatile("s_waitcnt vmcnt(0)" ::: "memory");                       \
        __builtin_amdgcn_s_barrier();                                          \
        __builtin_amdgcn_sched_barrier(0);                                     \
        _Pragma("unroll")                                                      \
        for (int ss = 0; ss < 12; ++ss) { QKV_STEP((BASE) + ss, ss & 1); }     \
    }

    if (half == 0) { QKV_RUN(0); } else { QKV_RUN(12); }
#undef QKV_RUN
#undef QKV_STEP
#undef STW
}

// ---------------------------------------------------------------------------
// k_attn (fused attn + Wo proj; exact R9/R12 structure — best measured).
// exp2f softmax (log2e folded into QSCALE upstream). LDS 80 KB -> 2 blk/CU.
// ---------------------------------------------------------------------------
__global__ __launch_bounds__(512, 2) void k_attn(const f16* __restrict__ Qo,
                                                 const f16* __restrict__ Ko,
                                                 const f16* __restrict__ VW,
                                                 const f16* __restrict__ Wsw,
                                                 f16* __restrict__ OUT) {
    __shared__ f16 Ks[128 * 256];   // 64 KB (AOs overlays part of it later)
    __shared__ f16 Qs[32 * 256];    // 16 KB

    const int tid  = threadIdx.x;
    const int idx  = blockIdx.x;
    const int lin  = (idx & 7) * 128 + (idx >> 3);   // contiguous (b,c) per XCD
    const int b    = lin >> 9;
    const int c    = lin & 511;
    const int h    = tid >> 6;
    const int l31  = tid & 31;
    const int hi   = (tid & 63) >> 5;

    const int u0 = 32 * c - 48;
    const int e0 = (32 * c + 80 < Mg) ? (32 * c + 80) : Mg;
    const bool full = (u0 >= 0) && (32 * c + 80 <= Mg);

    // ---- stage K window: 8 coalesced gll16 / thread
    const f16* Kb = Ko + (size_t)b * Mg * 256;
#pragma unroll
    for (int i = 0; i < 8; ++i) {
        int g = i * 512 + tid;
        int r = g >> 5, s = g & 31;
        int m = u0 + r;
        m = m < 0 ? 0 : (m > Mg - 1 ? Mg - 1 : m);
        gll16(Kb + (size_t)m * 256 + ((s ^ (r & 31)) << 3), &Ks[g * 8]);
    }
    // ---- stage Q tile: 2 coalesced gll16 / thread
    const f16* Qb = Qo + ((size_t)b * Mg + 32 * c) * 256;
#pragma unroll
    for (int i = 0; i < 2; ++i) {
        int g = i * 512 + tid;
        int r = g >> 5, s = g & 31;
        gll16(Qb + (size_t)r * 256 + ((s ^ r) << 3), &Qs[g * 8]);
    }
    __syncthreads();

    // ---- V loads direct to registers, issued early
    const f16* Vbb = VW + (size_t)b * 2048 * 256 * 8;
    f16x4 v0r[8], v1r[8];
#pragma unroll
    for (int s = 0; s < 8; ++s) {
        int g0 = (u0 >> 3) + 2 * s;
        int g1 = g0 + 1;
        g0 = g0 < 0 ? 0 : (g0 > 2047 ? 2047 : g0);
        g1 = g1 < 0 ? 0 : (g1 > 2047 ? 2047 : g1);
        v0r[s] = *(const f16x4*)(Vbb + ((size_t)g0 * 256 + 32 * h + l31) * 8 + 4 * hi);
        v1r[s] = *(const f16x4*)(Vbb + ((size_t)g1 * 256 + 32 * h + l31) * 8 + 4 * hi);
    }

    // ---- Q fragments from LDS (key = row = l31)
    f16x8 qf0 = *(const f16x8*)&Qs[l31 * 256 + (((4 * h + hi) ^ l31) << 3)];
    f16x8 qf1 = *(const f16x8*)&Qs[l31 * 256 + (((4 * h + 2 + hi) ^ l31) << 3)];

    // ---- QK^T from LDS
    f32x16 p4[4];
#pragma unroll
    for (int t = 0; t < 4; ++t)
#pragma unroll
        for (int e = 0; e < 16; ++e) p4[t][e] = 0.f;

    __builtin_amdgcn_s_setprio(1);
#pragma unroll
    for (int t = 0; t < 4; ++t) {
        int rr = 32 * t + l31;
        f16x8 kf0 = *(const f16x8*)&Ks[rr * 256 + (((4 * h + hi) ^ l31) << 3)];
        f16x8 kf1 = *(const f16x8*)&Ks[rr * 256 + (((4 * h + 2 + hi) ^ l31) << 3)];
        p4[t] = MFMA(kf0, qf0, p4[t]);
        p4[t] = MFMA(kf1, qf1, p4[t]);
    }
    __builtin_amdgcn_s_setprio(0);

    // ---- in-register softmax (scores already in log2 domain)
    float mx = -3e38f;
    float sum = 0.f;
    if (full) {
#pragma unroll
        for (int t = 0; t < 4; ++t)
#pragma unroll
            for (int r = 0; r < 16; ++r) mx = fmaxf(mx, p4[t][r]);
        mx = fmaxf(mx, __shfl_xor(mx, 32));
#pragma unroll
        for (int t = 0; t < 4; ++t)
#pragma unroll
            for (int r = 0; r < 16; ++r) {
                float ev = exp2f(p4[t][r] - mx);
                p4[t][r] = ev;
                sum += ev;
            }
    } else {
#pragma unroll
        for (int t = 0; t < 4; ++t)
#pragma unroll
            for (int r = 0; r < 16; ++r) {
                int gm = u0 + 32 * t + (r & 3) + 8 * (r >> 2) + 4 * hi;
                if (gm >= 0 && gm < e0) mx = fmaxf(mx, p4[t][r]);
            }
        mx = fmaxf(mx, __shfl_xor(mx, 32));
#pragma unroll
        for (int t = 0; t < 4; ++t)
#pragma unroll
            for (int r = 0; r < 16; ++r) {
                int gm = u0 + 32 * t + (r & 3) + 8 * (r >> 2) + 4 * hi;
                float ev = (gm >= 0 && gm < e0) ? exp2f(p4[t][r] - mx) : 0.f;
                p4[t][r] = ev;
                sum += ev;
            }
    }
    sum += __shfl_xor(sum, 32);
    const float inv = 1.f / sum;
#pragma unroll
    for (int t = 0; t < 4; ++t)
#pragma unroll
        for (int e = 0; e < 16; ++e) p4[t][e] *= inv;

    // ---- PV (all-register; V loads drained here)
    asm volatile("s_waitcnt vmcnt(0)" ::: "memory");
    __builtin_amdgcn_sched_barrier(0);

    f32x16 o;
#pragma unroll
    for (int e = 0; e < 16; ++e) o[e] = 0.f;

    __builtin_amdgcn_s_setprio(1);
#pragma unroll
    for (int s = 0; s < 8; ++s) {
        f16x8 pa;
#pragma unroll
        for (int e = 0; e < 8; ++e) pa[e] = (f16)(p4[s >> 1][8 * (s & 1) + e]);
        o = MFMA(pa, mk8(v0r[s], v1r[s]), o);
    }
    __builtin_amdgcn_s_setprio(0);

    // ---- AOs overlays K LDS (QK^T reads done after this barrier)
    __syncthreads();
    {
        const int col = h * 32 + l31;
#pragma unroll
        for (int r = 0; r < 16; ++r) {
            int row = (r & 3) + 8 * (r >> 2) + 4 * hi;
            Ks[row * 264 + col] = (f16)o[r];
        }
    }
    __syncthreads();

    // ---- phase 2: OUT[:, 32h..32h+31] = AO x Wo
    {
        const f16* Wb = Wsw + 3 * 65536;
        f32x16 acc;
#pragma unroll
        for (int e = 0; e < 16; ++e) acc[e] = 0.f;
        __builtin_amdgcn_s_setprio(1);
#pragma unroll
        for (int g = 0; g < 16; ++g) {
            int gp = 2 * g + hi;
            f16x8 av = *(const f16x8*)&Ks[l31 * 264 + gp * 8];
            f16x8 bv = *(const f16x8*)(Wb + ((size_t)gp * 256 + 32 * h + l31) * 8);
            acc = MFMA(av, bv, acc);
        }
        __builtin_amdgcn_s_setprio(0);
#pragma unroll
        for (int r = 0; r < 16; ++r) {
            int row = (r & 3) + 8 * (r >> 2) + 4 * hi;
            OUT[((size_t)b * Mg + 32 * c + row) * 256 + h * 32 + l31] = (f16)acc[r];
        }
    }
}

// ---------------------------------------------------------------------------
// k_seg v2: wave-per-token, f16x4-per-lane (G13 vectorization).
// grid (512, 2), block 256 = 4 waves; wave w owns token 4*bx+w; lane owns
// dims [4*lane, 4*lane+4). mask load is wave-uniform (broadcast).
// (ref applies mask twice -> msk^2 weighting)
// ---------------------------------------------------------------------------
__global__ __launch_bounds__(256) void k_seg(const f16* __restrict__ OUT,
                                             const int* __restrict__ starts,
                                             const float* __restrict__ mask,
                                             float* __restrict__ out) {
    const int b    = blockIdx.y;
    const int t    = blockIdx.x * 4 + (threadIdx.x >> 6);
    const int lane = threadIdx.x & 63;
    const int d4   = lane * 4;

    const int lo  = starts[b * 2049 + t];
    const int lo2 = starts[b * 2049 + t + 1];

    float s0 = 0.f, s1 = 0.f, s2 = 0.f, s3 = 0.f, cnt = 0.f;
    for (int m = lo; m < lo2; ++m) {
        float msk = mask[b * Mg + m];
        f16x4 v = *reinterpret_cast<const f16x4*>(OUT + ((size_t)b * Mg + m) * 256 + d4);
        float w2 = msk * msk;
        s0 += w2 * (float)v[0];
        s1 += w2 * (float)v[1];
        s2 += w2 * (float)v[2];
        s3 += w2 * (float)v[3];
        cnt += msk;
    }
    const float inv = 1.f / (cnt + 1e-8f);
    float4 res = { s0 * inv, s1 * inv, s2 * inv, s3 * inv };
    *reinterpret_cast<float4*>(out + ((size_t)b * Ntok + t) * 256 + d4) = res;
}

// ---------------------------------------------------------------------------
extern "C" void kernel_launch(void* const* d_in, const int* in_sizes, int n_in,
                              void* d_out, int out_size, void* d_ws, size_t ws_size,
                              hipStream_t stream) {
    const float* f_atom = (const float*)d_in[0];
    const float* amask  = (const float*)d_in[1];
    const float* Wq     = (const float*)d_in[2];
    const float* Wk     = (const float*)d_in[3];
    const float* Wv     = (const float*)d_in[4];
    const float* Wo     = (const float*)d_in[5];
    const int*   uid    = (const int*)d_in[6];

    const size_t HALF_WT  = 4 * 65536;
    const size_t HALF_MAT = (size_t)Bg * Mg * Dg;
    const size_t needed_bytes = (HALF_WT + 4 * HALF_MAT) * sizeof(f16) + 2 * 2049 * sizeof(int);
    if (ws_size < needed_bytes) return;

    f16* Wsw  = (f16*)d_ws;
    f16* Qb   = Wsw + HALF_WT;
    f16* Kb   = Qb + HALF_MAT;
    f16* VWb  = Kb + HALF_MAT;
    f16* OUTb = VWb + HALF_MAT;
    int* starts = (int*)(OUTb + HALF_MAT);

    k_wt  <<<dim3(1024), 256, 0, stream>>>(Wq, Wk, Wv, Wo, uid, Wsw, starts);
    k_qkv <<<dim3(512), 256, 0, stream>>>(f_atom, Wsw, Qb, Kb, VWb);
    k_attn<<<dim3(1024), 512, 0, stream>>>(Qb, Kb, VWb, Wsw, OUTb);
    k_seg <<<dim3(512, Bg), 256, 0, stream>>>(OUTb, starts, amask, (float*)d_out);
}